// Round 15
// baseline (291.005 us; speedup 1.0000x reference)
//
#include <hip/hip_runtime.h>
#include <hip/hip_bf16.h>

#define BATCH 16
#define SEQ   1024
#define DM    512
#define DSTATE 64
#define DIN   1024
#define NH    16
#define CONVDIM 1152
#define DINPROJ 2192
#define NPAD  2304
#define XDTW  1280   // xdt buffer row width (cols 1024..2303 of zxbcdt)
#define OC    1024
#define EPSF  1e-5f

typedef __attribute__((ext_vector_type(8))) short short8;
typedef __attribute__((ext_vector_type(4))) float f32x4;

__device__ __forceinline__ void g2lds16(const __hip_bfloat16* g, __hip_bfloat16* l) {
  __builtin_amdgcn_global_load_lds(
      (const __attribute__((address_space(1))) void*)g,
      (__attribute__((address_space(3))) void*)l, 16, 0, 0);
}

__device__ __forceinline__ float siluf(float x) { return x / (1.f + expf(-x)); }
__device__ __forceinline__ float b2f(unsigned short u) {
  return __uint_as_float(((unsigned int)u) << 16);
}
__device__ __forceinline__ unsigned short f2b(float v) {
  __hip_bfloat16 h = __float2bfloat16(v);
  return __builtin_bit_cast(unsigned short, h);
}

// ---------------- gemm1: zxbcdt = x @ in_proj^T, split dest (z | xdt) --------
// double-buffered 2-phase (issue-early stage), 64 KB LDS, 1 barrier/iter.
__global__ __launch_bounds__(256) void gemm1_kernel(
    const __hip_bfloat16* __restrict__ A,
    const __hip_bfloat16* __restrict__ B,
    __hip_bfloat16* __restrict__ zbuf,
    __hip_bfloat16* __restrict__ xdt)
{
  __shared__ __hip_bfloat16 sAB[2][2][8192];  // [buf][A/B][128*64]
  const int tid  = threadIdx.x;
  const int lane = tid & 63;
  const int wid  = tid >> 6;
  const int wr = wid >> 1, wc = wid & 1;
  const long row0 = (long)blockIdx.x * 128;
  const int  col0 = blockIdx.y * 128;
  const __hip_bfloat16* Ab = A + row0 * 512;
  const __hip_bfloat16* Bb = B + (long)col0 * 512;

  auto stage = [&](int kt, int buf) {
#pragma unroll
    for (int it = 0; it < 4; ++it) {
      int idx = it * 256 + tid;
      int r = idx >> 3;
      int kk = (idx & 7) << 3;
      g2lds16(Ab + (long)r * 512 + kt + kk, &sAB[buf][0][idx * 8]);
      g2lds16(Bb + (long)r * 512 + kt + kk, &sAB[buf][1][idx * 8]);
    }
  };

  f32x4 acc[4][4] = {};
  stage(0, 0);
  __syncthreads();
  int cur = 0;
  for (int kt = 0; kt < 512; kt += 64) {
    if (kt + 64 < 512) stage(kt + 64, cur ^ 1);
    const __hip_bfloat16* sA = &sAB[cur][0][0];
    const __hip_bfloat16* sB = &sAB[cur][1][0];
#pragma unroll
    for (int kk = 0; kk < 64; kk += 32) {
      const int kl = kk + (lane >> 4) * 8;
      short8 af[4], bfr[4];
#pragma unroll
      for (int m = 0; m < 4; ++m)
        af[m] = *(const short8*)(sA + (wr * 64 + m * 16 + (lane & 15)) * 64 + kl);
#pragma unroll
      for (int n = 0; n < 4; ++n)
        bfr[n] = *(const short8*)(sB + (wc * 64 + n * 16 + (lane & 15)) * 64 + kl);
#pragma unroll
      for (int m = 0; m < 4; ++m)
#pragma unroll
        for (int n = 0; n < 4; ++n)
          acc[m][n] = __builtin_amdgcn_mfma_f32_16x16x32_bf16(af[m], bfr[n], acc[m][n], 0, 0, 0);
    }
    __syncthreads();  // drains stage loads; protects buf overwrite
    cur ^= 1;
  }

  __hip_bfloat16* Cb;
  int ldc, coff;
  if (col0 < 1024) { Cb = zbuf; ldc = 1024; coff = col0; }
  else             { Cb = xdt;  ldc = XDTW; coff = col0 - 1024; }
  const int rb = (int)row0 + wr * 64 + ((lane >> 4) << 2);
  const int cb = coff + wc * 64 + (lane & 15);
#pragma unroll
  for (int m = 0; m < 4; ++m)
#pragma unroll
    for (int n = 0; n < 4; ++n) {
      const int r = rb + m * 16, cc = cb + n * 16;
#pragma unroll
      for (int q = 0; q < 4; ++q)
        Cb[(long)(r + q) * ldc + cc] = __float2bfloat16(acc[m][n][q]);
    }
}

// ---------------- gemm2: u = y_raw @ (out_proj*rms_w)^T, rn-scaled, ----------
// writes uTp TRANSPOSED bf16. Double-buffered LDS (64 KB), 1 barrier/iter.
__global__ __launch_bounds__(256) void gemm2_trans_kernel(
    const __hip_bfloat16* __restrict__ A,     // ypb (unnormalized) [16384][1024]
    const __hip_bfloat16* __restrict__ B,     // w2b' [512][1024]
    const float* __restrict__ rn,             // [16384] row scales
    __hip_bfloat16* __restrict__ uTp)
{
  __shared__ unsigned short smem[2][2][8192];  // 64 KB: [buf][A/B][128*64]
  const int tid  = threadIdx.x;
  const int lane = tid & 63;
  const int wid  = tid >> 6;
  const int wr = wid >> 1, wc = wid & 1;
  const long row0 = (long)blockIdx.x * 128;   // (b,l) rows
  const int  col0 = blockIdx.y * 128;         // s cols
  const int  b  = (int)(row0 >> 10);
  const int  l0 = (int)(row0 & 1023);
  const __hip_bfloat16* Ab = A + row0 * 1024;
  const __hip_bfloat16* Bb = B + (long)col0 * 1024;

  auto stage = [&](int kt, int buf) {
#pragma unroll
    for (int it = 0; it < 4; ++it) {
      int idx = it * 256 + tid;
      int r = idx >> 3;
      int kk = (idx & 7) << 3;
      g2lds16(Ab + (long)r * 1024 + kt + kk, (__hip_bfloat16*)&smem[buf][0][idx * 8]);
      g2lds16(Bb + (long)r * 1024 + kt + kk, (__hip_bfloat16*)&smem[buf][1][idx * 8]);
    }
  };

  f32x4 acc[4][4] = {};
  stage(0, 0);
  __syncthreads();
  int cur = 0;
  for (int kt = 0; kt < 1024; kt += 64) {
    if (kt + 64 < 1024) stage(kt + 64, cur ^ 1);
    const __hip_bfloat16* sA = (const __hip_bfloat16*)&smem[cur][0][0];
    const __hip_bfloat16* sB = (const __hip_bfloat16*)&smem[cur][1][0];
#pragma unroll
    for (int kk = 0; kk < 64; kk += 32) {
      const int kl = kk + (lane >> 4) * 8;
      short8 af[4], bfr[4];
#pragma unroll
      for (int m = 0; m < 4; ++m)
        af[m] = *(const short8*)(sA + (wr * 64 + m * 16 + (lane & 15)) * 64 + kl);
#pragma unroll
      for (int n = 0; n < 4; ++n)
        bfr[n] = *(const short8*)(sB + (wc * 64 + n * 16 + (lane & 15)) * 64 + kl);
#pragma unroll
      for (int m = 0; m < 4; ++m)
#pragma unroll
        for (int n = 0; n < 4; ++n)
          acc[m][n] = __builtin_amdgcn_mfma_f32_16x16x32_bf16(af[m], bfr[n], acc[m][n], 0, 0, 0);
    }
    __syncthreads();  // drains stage loads; also protects buf overwrite
    cur ^= 1;
  }

  // rn-scale + transpose: acc(r,c) -> sT[c_local][r_local]  (c = s, r = l)
  unsigned short* sT = &smem[0][0][0];  // first 32 KB, contiguous 128*128
  const int rl = wr * 64 + ((lane >> 4) << 2);
  const int cl = wc * 64 + (lane & 15);
#pragma unroll
  for (int m = 0; m < 4; ++m) {
    float rnv[4];
#pragma unroll
    for (int q = 0; q < 4; ++q) rnv[q] = rn[row0 + rl + m * 16 + q];
#pragma unroll
    for (int n = 0; n < 4; ++n) {
      const int c = cl + n * 16;
#pragma unroll
      for (int q = 0; q < 4; ++q)
        sT[c * 128 + rl + m * 16 + q] = f2b(acc[m][n][q] * rnv[q]);
    }
  }
  __syncthreads();

  // coalesced out: wave w handles rows w*32..w*32+31; lane covers 2 l's
  unsigned short* up = (unsigned short*)uTp + (long)b * 514 * 1024;
  const int w = tid >> 6;
#pragma unroll
  for (int k = 0; k < 32; ++k) {
    const int row = w * 32 + k;  // s_local
    ushort2 o2;
    o2.x = sT[row * 128 + lane * 2];
    o2.y = sT[row * 128 + lane * 2 + 1];
    *(ushort2*)(up + (long)(col0 + row + 1) * 1024 + l0 + lane * 2) = o2;
  }
}

// ---------------- conv-as-GEMM: C[n] = W'(1024x3072) @ Bvirt[n]^T -------------
// Bvirt[n][s][k*1024+i] = uTp[n][s+k][i]; XCD swizzle; dbuf 64 KB; bf16 out.
// round-13 proven form + NON-CONTENDED bn-stats partials (plain stores to
// unique slots; round-12's contended atomics cost +20us -- lesson applied).
__global__ __launch_bounds__(256) void gemm_conv_kernel(
    const __hip_bfloat16* __restrict__ A,     // W' [1024][3072]
    const __hip_bfloat16* __restrict__ uTp,   // [16][514][1024]
    __hip_bfloat16* __restrict__ C,           // [16][1024][512] bf16
    float* __restrict__ statspart)            // [2][128][1024]: sum | sumsq
{
  // bijective swizzle: XCD k gets contiguous g-range -> 2 whole batches
  const int f = blockIdx.x + 8 * (blockIdx.y + 4 * blockIdx.z);  // 0..511
  const int g = (f & 7) * 64 + (f >> 3);
  const int bx = g & 7, by = (g >> 3) & 3, bz = g >> 5;

  __shared__ __hip_bfloat16 sAB[2][2][8192];  // 64 KB: [buf][A/B][128*64]
  const int tid  = threadIdx.x;
  const int lane = tid & 63;
  const int wid  = tid >> 6;
  const int wr = wid >> 1, wc = wid & 1;
  const int row0 = bx * 128;
  const int col0 = by * 128;
  const __hip_bfloat16* Ab = A + (long)row0 * 3072;
  const __hip_bfloat16* Ub = uTp + (long)bz * 514 * 1024;

  auto stage = [&](int kt, int buf) {
    const int seg = kt >> 10;        // k tap (0..2)
    const int io  = kt & 1023;       // i offset within tap
#pragma unroll
    for (int it = 0; it < 4; ++it) {
      int idx = it * 256 + tid;
      int r = idx >> 3;
      int kk = (idx & 7) << 3;
      g2lds16(Ab + (long)r * 3072 + kt + kk, &sAB[buf][0][idx * 8]);
      g2lds16(Ub + (long)(col0 + r + seg) * 1024 + io + kk, &sAB[buf][1][idx * 8]);
    }
  };

  f32x4 acc[4][4] = {};
  stage(0, 0);
  __syncthreads();
  int cur = 0;
  for (int kt = 0; kt < 3072; kt += 64) {
    if (kt + 64 < 3072) stage(kt + 64, cur ^ 1);
    const __hip_bfloat16* sA = &sAB[cur][0][0];
    const __hip_bfloat16* sB = &sAB[cur][1][0];
#pragma unroll
    for (int kk = 0; kk < 64; kk += 32) {
      const int kl = kk + (lane >> 4) * 8;
      short8 af[4], bfr[4];
#pragma unroll
      for (int m = 0; m < 4; ++m)
        af[m] = *(const short8*)(sA + (wr * 64 + m * 16 + (lane & 15)) * 64 + kl);
#pragma unroll
      for (int n = 0; n < 4; ++n)
        bfr[n] = *(const short8*)(sB + (wc * 64 + n * 16 + (lane & 15)) * 64 + kl);
#pragma unroll
      for (int m = 0; m < 4; ++m)
#pragma unroll
        for (int n = 0; n < 4; ++n)
          acc[m][n] = __builtin_amdgcn_mfma_f32_16x16x32_bf16(af[m], bfr[n], acc[m][n], 0, 0, 0);
    }
    __syncthreads();
    cur ^= 1;
  }

  __hip_bfloat16* Cb = C + (long)bz * OC * DM;
  const int rb = row0 + wr * 64 + ((lane >> 4) << 2);
  const int cb = col0 + wc * 64 + (lane & 15);
#pragma unroll
  for (int m = 0; m < 4; ++m)
#pragma unroll
    for (int n = 0; n < 4; ++n) {
      const int r = rb + m * 16, cc = cb + n * 16;
#pragma unroll
      for (int q = 0; q < 4; ++q)
        Cb[(long)(r + q) * DM + cc] = __float2bfloat16(acc[m][n][q]);
    }

  // bn partials: shfl over 16-lane cc-group; PLAIN store to unique slot
  // slot = (by*16+bz)*2 + wc  (each (channel,slot) written exactly once)
  const int slot = ((by * 16 + bz) << 1) | wc;
#pragma unroll
  for (int m = 0; m < 4; ++m)
#pragma unroll
    for (int q = 0; q < 4; ++q) {
      float s = 0.f, s2 = 0.f;
#pragma unroll
      for (int n = 0; n < 4; ++n) { float v = acc[m][n][q]; s += v; s2 += v * v; }
      s  += __shfl_xor(s, 1);  s  += __shfl_xor(s, 2);
      s  += __shfl_xor(s, 4);  s  += __shfl_xor(s, 8);
      s2 += __shfl_xor(s2, 1); s2 += __shfl_xor(s2, 2);
      s2 += __shfl_xor(s2, 4); s2 += __shfl_xor(s2, 8);
      if ((lane & 15) == 0) {
        const int o = rb + m * 16 + q;
        statspart[(long)slot * 1024 + o] = s;
        statspart[131072L + (long)slot * 1024 + o] = s2;
      }
    }
}

// ---------------- fill (ws-guard diagnostics only) ---------------------------
__global__ __launch_bounds__(256) void fill_kernel(float* __restrict__ out, float v, long n) {
  long i = (long)blockIdx.x * 256 + threadIdx.x;
  if (i < n) out[i] = v;
}

// ---------------- fused prep: casts + reorders + rnacc zero ------------------
// blocks: [0,8192) x cast | [8192,9344) w1 pad-cast f4 | [9344,9856) w2*rms |
// [9856,13952) conv_w reorder | [13952,14016) rnacc zero
__global__ __launch_bounds__(256) void prep_kernel(
    const float* __restrict__ x, const float* __restrict__ w1,
    const float* __restrict__ w2, const float* __restrict__ rms_w,
    const float* __restrict__ w3,
    __hip_bfloat16* __restrict__ xbf, __hip_bfloat16* __restrict__ w1b,
    __hip_bfloat16* __restrict__ w2b, __hip_bfloat16* __restrict__ w3b,
    float* __restrict__ rnacc)
{
  const int bid = blockIdx.x;
  if (bid < 8192) {
    long i = (long)bid * 256 + threadIdx.x;   // 2,097,152 float4 groups
    float4 v = *(const float4*)(x + i * 4);
    __hip_bfloat16* o = xbf + i * 4;
    o[0] = __float2bfloat16(v.x);
    o[1] = __float2bfloat16(v.y);
    o[2] = __float2bfloat16(v.z);
    o[3] = __float2bfloat16(v.w);
  } else if (bid < 9344) {
    int i = (bid - 8192) * 256 + threadIdx.x;  // 294,912 float4 groups
    int r = i >> 7;                             // row (512-wide, 4-aligned)
    float4 v;
    if (r < DINPROJ) v = *(const float4*)(w1 + (long)i * 4);
    else { v.x = 0.f; v.y = 0.f; v.z = 0.f; v.w = 0.f; }
    __hip_bfloat16* o = w1b + (long)i * 4;
    o[0] = __float2bfloat16(v.x);
    o[1] = __float2bfloat16(v.y);
    o[2] = __float2bfloat16(v.z);
    o[3] = __float2bfloat16(v.w);
  } else if (bid < 9856) {
    int i = (bid - 9344) * 256 + threadIdx.x;  // 131072 groups of 4
    float4 v = *(const float4*)(w2 + (long)i * 4);
    float4 gw = *(const float4*)(rms_w + ((i * 4) & 1023));
    __hip_bfloat16* o = w2b + (long)i * 4;
    o[0] = __float2bfloat16(v.x * gw.x);
    o[1] = __float2bfloat16(v.y * gw.y);
    o[2] = __float2bfloat16(v.z * gw.z);
    o[3] = __float2bfloat16(v.w * gw.w);
  } else if (bid < 13952) {
    int t = (bid - 9856) * 256 + threadIdx.x;  // 1024*1024
    int o = t >> 10, i = t & 1023;
    const float* p = w3 + (long)o * 3072 + i * 3;
    __hip_bfloat16* q = w3b + (long)o * 3072 + i;
    q[0]    = __float2bfloat16(p[0]);
    q[1024] = __float2bfloat16(p[1]);
    q[2048] = __float2bfloat16(p[2]);
  } else {
    int i = (bid - 13952) * 256 + threadIdx.x;  // 16384 rnacc zeros
    rnacc[i] = 0.f;
  }
}

// ---------------- conv1d sliding-window, short walk (16) for occupancy -------
__global__ __launch_bounds__(256) void conv1d_slide_kernel(
    const __hip_bfloat16* __restrict__ xdt, const float* __restrict__ cw,
    const float* __restrict__ cb, const float* __restrict__ dt_bias,
    __hip_bfloat16* __restrict__ xbc, float* __restrict__ dtb)
{
  const int pair = blockIdx.x * 256 + threadIdx.x;
  const int c = pair * 2;                 // channel (even), < 1168 active
  if (c >= CONVDIM + NH) return;
  const int b  = blockIdx.z;
  const int l0 = blockIdx.y * 16;
  const long rowb = (long)b * SEQ;
  const unsigned short* src = (const unsigned short*)xdt + rowb * XDTW + c;

  if (c < CONVDIM) {
    const float4 wa = *(const float4*)(cw + c * 4);
    const float4 wb = *(const float4*)(cw + (c + 1) * 4);
    const float ba = cb[c], bb = cb[c + 1];
    float w0x, w0y, w1x, w1y, w2x, w2y;
    {
      ushort2 v;
      if (l0 >= 3) { v = *(const ushort2*)(src + (long)(l0 - 3) * XDTW); w0x = b2f(v.x); w0y = b2f(v.y); }
      else { w0x = 0.f; w0y = 0.f; }
      if (l0 >= 2) { v = *(const ushort2*)(src + (long)(l0 - 2) * XDTW); w1x = b2f(v.x); w1y = b2f(v.y); }
      else { w1x = 0.f; w1y = 0.f; }
      if (l0 >= 1) { v = *(const ushort2*)(src + (long)(l0 - 1) * XDTW); w2x = b2f(v.x); w2y = b2f(v.y); }
      else { w2x = 0.f; w2y = 0.f; }
    }
    unsigned short* dst = (unsigned short*)xbc + rowb * CONVDIM + c;
#pragma unroll
    for (int i = 0; i < 16; ++i) {
      const int l = l0 + i;
      const ushort2 v = *(const ushort2*)(src + (long)l * XDTW);
      const float xv0 = b2f(v.x), xv1 = b2f(v.y);
      float a0 = ba, a1 = bb;
      a0 += w0x * wa.x; a1 += w0y * wb.x;
      a0 += w1x * wa.y; a1 += w1y * wb.y;
      a0 += w2x * wa.z; a1 += w2y * wb.z;
      a0 += xv0 * wa.w; a1 += xv1 * wb.w;
      ushort2 o;
      o.x = f2b(siluf(a0));
      o.y = f2b(siluf(a1));
      *(ushort2*)(dst + (long)l * CONVDIM) = o;
      w0x = w1x; w0y = w1y; w1x = w2x; w1y = w2y; w2x = xv0; w2y = xv1;
    }
  } else {
    const int hh = c - CONVDIM;           // 0..14 (even)
    const float b0 = dt_bias[hh], b1 = dt_bias[hh + 1];
#pragma unroll
    for (int i = 0; i < 16; ++i) {
      const long l = l0 + i;
      const ushort2 v = *(const ushort2*)(src + l * XDTW);
      const float d0 = b2f(v.x) + b0, d1 = b2f(v.y) + b1;
      float2 o;
      o.x = fmaxf(d0, 0.f) + log1pf(expf(-fabsf(d0)));
      o.y = fmaxf(d1, 0.f) + log1pf(expf(-fabsf(d1)));
      *(float2*)(dtb + (rowb + l) * NH + hh) = o;
    }
  }
}

// ---------------- SSD chunked scan: phase 1 ----------------------------------
// outputs staged through dead LDS (sM/sBwT) -> coalesced ushort8 stores.
__global__ __launch_bounds__(256) void ssd_chunk_kernel(
    const __hip_bfloat16* __restrict__ xbc, const float* __restrict__ dtb,
    const float* __restrict__ A_log, __hip_bfloat16* __restrict__ ypre,
    __hip_bfloat16* __restrict__ Tbuf, float* __restrict__ Aprod)
{
  const int c = blockIdx.x, h = blockIdx.y, b = blockIdx.z;
  const int tid = threadIdx.x, lane = tid & 63, wid = tid >> 6;
  const int wr = wid >> 1, wc = wid & 1;
  const long r0 = (long)b * SEQ + c * 64;

  __shared__ unsigned short sB[64 * 72], sC[64 * 72], sXT[64 * 72],
                            sBwT[64 * 72], sM[64 * 72];
  __shared__ float sS[64], sDt[64];

  {
    const int j = tid >> 2, seg = (tid & 3) * 16;
    const unsigned short* row = (const unsigned short*)(xbc + (r0 + j) * CONVDIM);
    short8 v0 = *(const short8*)(row + DIN + seg);
    short8 v1 = *(const short8*)(row + DIN + seg + 8);
    *(short8*)&sB[j * 72 + seg] = v0;
    *(short8*)&sB[j * 72 + seg + 8] = v1;
    v0 = *(const short8*)(row + DIN + DSTATE + seg);
    v1 = *(const short8*)(row + DIN + DSTATE + seg + 8);
    *(short8*)&sC[j * 72 + seg] = v0;
    *(short8*)&sC[j * 72 + seg + 8] = v1;
    short8 x0 = *(const short8*)(row + h * 64 + seg);
    short8 x1 = *(const short8*)(row + h * 64 + seg + 8);
#pragma unroll
    for (int e = 0; e < 8; ++e) {
      sXT[(seg + e) * 72 + j] = (unsigned short)x0[e];
      sXT[(seg + 8 + e) * 72 + j] = (unsigned short)x1[e];
    }
  }
  if (tid < 64) {
    float dt = dtb[(r0 + tid) * NH + h];
    float s = -__expf(A_log[h]) * dt;
#pragma unroll
    for (int off = 1; off < 64; off <<= 1) {
      float o = __shfl_up(s, off);
      if (lane >= off) s += o;
    }
    sDt[tid] = dt;
    sS[tid] = s;
    if (tid == 63) Aprod[((b * 16 + h) * 16) + c] = __expf(s);
  }
  __syncthreads();

  {
    const int j = tid >> 2, n0 = (tid & 3) * 16;
    const float w = __expf(sS[63] - sS[j]) * sDt[j];
#pragma unroll
    for (int e = 0; e < 16; ++e)
      sBwT[(n0 + e) * 72 + j] = f2b(w * b2f(sB[j * 72 + n0 + e]));
  }
  {
    f32x4 acc1[2][2] = {};
#pragma unroll
    for (int kk = 0; kk < 64; kk += 32) {
      const int kl = kk + (lane >> 4) * 8;
      short8 af[2], bfr[2];
#pragma unroll
      for (int m = 0; m < 2; ++m)
        af[m] = *(const short8*)&sC[(wr * 32 + m * 16 + (lane & 15)) * 72 + kl];
#pragma unroll
      for (int n = 0; n < 2; ++n)
        bfr[n] = *(const short8*)&sB[(wc * 32 + n * 16 + (lane & 15)) * 72 + kl];
#pragma unroll
      for (int m = 0; m < 2; ++m)
#pragma unroll
        for (int n = 0; n < 2; ++n)
          acc1[m][n] = __builtin_amdgcn_mfma_f32_16x16x32_bf16(af[m], bfr[n], acc1[m][n], 0, 0, 0);
    }
    const int rq = (lane >> 4) * 4, cc = lane & 15;
#pragma unroll
    for (int m = 0; m < 2; ++m)
#pragma unroll
      for (int n = 0; n < 2; ++n)
#pragma unroll
        for (int q = 0; q < 4; ++q) {
          const int i = wr * 32 + m * 16 + rq + q;
          const int jj = wc * 32 + n * 16 + cc;
          float f = (jj <= i) ? __expf(sS[i] - sS[jj]) * sDt[jj] : 0.f;
          sM[i * 72 + jj] = f2b(acc1[m][n][q] * f);
        }
  }
  __syncthreads();

  f32x4 acc2[2][2] = {}, acc3[2][2] = {};
#pragma unroll
  for (int kk = 0; kk < 64; kk += 32) {
    const int kl = kk + (lane >> 4) * 8;
    short8 am[2], axB[2], axA[2], abw[2];
#pragma unroll
    for (int m = 0; m < 2; ++m) {
      am[m]  = *(const short8*)&sM[(wr * 32 + m * 16 + (lane & 15)) * 72 + kl];
      axA[m] = *(const short8*)&sXT[(wr * 32 + m * 16 + (lane & 15)) * 72 + kl];
    }
#pragma unroll
    for (int n = 0; n < 2; ++n) {
      axB[n] = *(const short8*)&sXT[(wc * 32 + n * 16 + (lane & 15)) * 72 + kl];
      abw[n] = *(const short8*)&sBwT[(wc * 32 + n * 16 + (lane & 15)) * 72 + kl];
    }
#pragma unroll
    for (int m = 0; m < 2; ++m)
#pragma unroll
      for (int n = 0; n < 2; ++n) {
        acc2[m][n] = __builtin_amdgcn_mfma_f32_16x16x32_bf16(am[m], axB[n], acc2[m][n], 0, 0, 0);
        acc3[m][n] = __builtin_amdgcn_mfma_f32_16x16x32_bf16(axA[m], abw[n], acc3[m][n], 0, 0, 0);
      }
  }
  __syncthreads();  // all waves done reading sM/sBwT -> safe to reuse
  {
    const int rq = (lane >> 4) * 4, cc = lane & 15;
#pragma unroll
    for (int m = 0; m < 2; ++m)
#pragma unroll
      for (int n = 0; n < 2; ++n)
#pragma unroll
        for (int q = 0; q < 4; ++q) {
          const int i = wr * 32 + m * 16 + rq + q;
          const int pj = wc * 32 + n * 16 + cc;
          sM[i * 72 + pj]   = f2b(acc2[m][n][q]);
          sBwT[i * 72 + pj] = f2b(acc3[m][n][q]);
        }
  }
  __syncthreads();
  {
    const int j = tid >> 2, seg = (tid & 3) * 16;
    unsigned short* yp = (unsigned short*)ypre + (r0 + j) * DIN + h * 64 + seg;
    *(short8*)yp       = *(const short8*)&sM[j * 72 + seg];
    *(short8*)(yp + 8) = *(const short8*)&sM[j * 72 + seg + 8];
    const long tb = (((long)(b * 16 + h)) * 16 + c) * 4096;
    unsigned short* tp = (unsigned short*)Tbuf + tb + j * 64 + seg;
    *(short8*)tp       = *(const short8*)&sBwT[j * 72 + seg];
    *(short8*)(tp + 8) = *(const short8*)&sBwT[j * 72 + seg + 8];
  }
}

// ---------------- SSD phase 2: sequential inter-chunk state ------------------
__global__ __launch_bounds__(1024) void ssd_state_kernel(
    __hip_bfloat16* __restrict__ Tbuf, const float* __restrict__ Aprod)
{
  const int bh = blockIdx.x;
  const int t = threadIdx.x;
  float h0 = 0.f, h1 = 0.f, h2 = 0.f, h3 = 0.f;
  unsigned short* base = (unsigned short*)Tbuf + (long)bh * 16 * 4096 + t * 4;
  for (int c = 0; c < 16; ++c) {
    unsigned short* p = base + (long)c * 4096;
    ushort4 tv = *(const ushort4*)p;
    ushort4 hv;
    hv.x = f2b(h0); hv.y = f2b(h1); hv.z = f2b(h2); hv.w = f2b(h3);
    *(ushort4*)p = hv;
    const float ap = Aprod[bh * 16 + c];
    h0 = h0 * ap + b2f(tv.x);
    h1 = h1 * ap + b2f(tv.y);
    h2 = h2 * ap + b2f(tv.z);
    h3 = h3 * ap + b2f(tv.w);
  }
}

// ---------------- SSD phase 3: Y += exp(s_i)*C@H^T + D*x; gate; rn partials --
// shfl row-reduce (round-11); output staged via dead sC -> coalesced stores.
__global__ __launch_bounds__(256) void ssd_out_kernel(
    const __hip_bfloat16* __restrict__ xbc, const float* __restrict__ dtb,
    const float* __restrict__ A_log, const __hip_bfloat16* __restrict__ Hbuf,
    const __hip_bfloat16* __restrict__ zbuf, const float* __restrict__ Dv,
    __hip_bfloat16* __restrict__ ypre, float* __restrict__ rnacc)
{
  const int c = blockIdx.x, h = blockIdx.y, b = blockIdx.z;
  const int tid = threadIdx.x, lane = tid & 63, wid = tid >> 6;
  const int wr = wid >> 1, wc = wid & 1;
  const long r0 = (long)b * SEQ + c * 64;

  __shared__ unsigned short sC[64 * 72], sH[64 * 72];
  __shared__ float sS[64];
  __shared__ float sRedW[2][64];   // [wc][row] per-wave partials (no conflicts)

  {
    const int j = tid >> 2, seg = (tid & 3) * 16;
    const unsigned short* row = (const unsigned short*)(xbc + (r0 + j) * CONVDIM);
    short8 v0 = *(const short8*)(row + DIN + DSTATE + seg);
    short8 v1 = *(const short8*)(row + DIN + DSTATE + seg + 8);
    *(short8*)&sC[j * 72 + seg] = v0;
    *(short8*)&sC[j * 72 + seg + 8] = v1;
    const unsigned short* hrow =
        (const unsigned short*)Hbuf + (((long)(b * 16 + h)) * 16 + c) * 4096 + j * 64;
    v0 = *(const short8*)(hrow + seg);
    v1 = *(const short8*)(hrow + seg + 8);
    *(short8*)&sH[j * 72 + seg] = v0;
    *(short8*)&sH[j * 72 + seg + 8] = v1;
  }
  if (tid < 64) {
    float dt = dtb[(r0 + tid) * NH + h];
    float s = -__expf(A_log[h]) * dt;
#pragma unroll
    for (int off = 1; off < 64; off <<= 1) {
      float o = __shfl_up(s, off);
      if (lane >= off) s += o;
    }
    sS[tid] = s;
  }
  __syncthreads();

  f32x4 acc[2][2] = {};
#pragma unroll
  for (int kk = 0; kk < 64; kk += 32) {
    const int kl = kk + (lane >> 4) * 8;
    short8 af[2], bfr[2];
#pragma unroll
    for (int m = 0; m < 2; ++m)
      af[m] = *(const short8*)&sC[(wr * 32 + m * 16 + (lane & 15)) * 72 + kl];
#pragma unroll
    for (int n = 0; n < 2; ++n)
      bfr[n] = *(const short8*)&sH[(wc * 32 + n * 16 + (lane & 15)) * 72 + kl];
#pragma unroll
    for (int m = 0; m < 2; ++m)
#pragma unroll
      for (int n = 0; n < 2; ++n)
        acc[m][n] = __builtin_amdgcn_mfma_f32_16x16x32_bf16(af[m], bfr[n], acc[m][n], 0, 0, 0);
  }
  __syncthreads();  // all MFMA reads of sC done -> reuse sC for output staging
  const float Dh = Dv[h];
  const int rq = (lane >> 4) * 4, cc = lane & 15;
  float rsum[2][4] = {};
#pragma unroll
  for (int m = 0; m < 2; ++m)
#pragma unroll
    for (int n = 0; n < 2; ++n)
#pragma unroll
      for (int q = 0; q < 4; ++q) {
        const int i = wr * 32 + m * 16 + rq + q;
        const int p = wc * 32 + n * 16 + cc;
        const long r = r0 + i;
        const long oidx = r * DIN + h * 64 + p;
        float yv = b2f(((const unsigned short*)ypre)[oidx]);
        float xv = b2f(((const unsigned short*)xbc)[r * CONVDIM + h * 64 + p]);
        float zv = b2f(((const unsigned short*)zbuf)[r * DIN + h * 64 + p]);
        yv += __expf(sS[i]) * acc[m][n][q] + Dh * xv;
        const float g = yv * siluf(zv);
        rsum[m][q] += g * g;
        sC[i * 72 + p] = f2b(g);
      }
  // wave-parallel row reduce: 16-lane column group -> shfl tree -> plain store
#pragma unroll
  for (int m = 0; m < 2; ++m)
#pragma unroll
    for (int q = 0; q < 4; ++q) {
      float v = rsum[m][q];
      v += __shfl_xor(v, 1);
      v += __shfl_xor(v, 2);
      v += __shfl_xor(v, 4);
      v += __shfl_xor(v, 8);
      if ((lane & 15) == 0)
        sRedW[wc][wr * 32 + m * 16 + rq + q] = v;
    }
  __syncthreads();
  {
    const int j = tid >> 2, seg = (tid & 3) * 16;
    unsigned short* yp = (unsigned short*)ypre + (r0 + j) * DIN + h * 64 + seg;
    *(short8*)yp       = *(const short8*)&sC[j * 72 + seg];
    *(short8*)(yp + 8) = *(const short8*)&sC[j * 72 + seg + 8];
  }
  if (tid < 64) atomicAdd(&rnacc[r0 + tid], sRedW[0][tid] + sRedW[1][tid]);
}

// ---------------- rn finalize + uTp pad-row zero (fused small launch) --------
__global__ __launch_bounds__(256) void rnfin_pad_kernel(
    const float* __restrict__ rnacc, float* __restrict__ rn,
    __hip_bfloat16* __restrict__ uTp)
{
  const int bid = blockIdx.x;
  if (bid < 64) {
    int i = bid * 256 + threadIdx.x;  // 16384
    rn[i] = rsqrtf(rnacc[i] * (1.f / DIN) + EPSF);
  } else {
    int t = (bid - 64) * 256 + threadIdx.x;  // 32768
    int n = t >> 11, w = t & 2047;
    long row = (w >> 10) ? 513 : 0;
    uTp[(long)n * 514 * 1024 + row * 1024 + (w & 1023)] = __float2bfloat16(0.f);
  }
}

// ---------------- bn stats finalize from gemm_conv partials ------------------
// thread = channel; coalesced reads (consecutive o adjacent per slot row)
__global__ __launch_bounds__(256) void bnfin_kernel(
    const float* __restrict__ statspart, float* __restrict__ stats)
{
  const int o = blockIdx.x * 256 + threadIdx.x;  // 0..1023
  float s = 0.f, s2 = 0.f;
  for (int i = 0; i < 128; ++i) {
    s  += statspart[(long)i * 1024 + o];
    s2 += statspart[131072L + (long)i * 1024 + o];
  }
  const float mean = s * (1.f / 8192.f);
  const float var = s2 * (1.f / 8192.f) - mean * mean;
  stats[o] = mean;
  stats[OC + o] = rsqrtf(var + EPSF);
}

__global__ __launch_bounds__(256) void bn_silu_kernel(
    const __hip_bfloat16* __restrict__ c, const float* __restrict__ stats,
    const float* __restrict__ gamma, const float* __restrict__ beta,
    float* __restrict__ out)
{
  long gid = (long)blockIdx.x * 256 + threadIdx.x;
  long base = gid * 4;
  int o = (int)((base >> 9) & (OC - 1));
  float mean = stats[o], rstd = stats[OC + o];
  float g = gamma[o] * rstd;
  float sh = beta[o] - mean * g;
  ushort4 v = *(const ushort4*)((const unsigned short*)c + base);
  float4 r;
  r.x = siluf(b2f(v.x) * g + sh);
  r.y = siluf(b2f(v.y) * g + sh);
  r.z = siluf(b2f(v.z) * g + sh);
  r.w = siluf(b2f(v.w) * g + sh);
  *(float4*)(out + base) = r;
}

// ---------------- launcher ---------------------------------------------------
extern "C" void kernel_launch(void* const* d_in, const int* in_sizes, int n_in,
                              void* d_out, int out_size, void* d_ws, size_t ws_size,
                              hipStream_t stream) {
  const float* x         = (const float*)d_in[0];
  const float* in_projw  = (const float*)d_in[1];
  const float* conv1dw   = (const float*)d_in[2];
  const float* conv1db   = (const float*)d_in[3];
  const float* dt_bias   = (const float*)d_in[4];
  const float* A_log     = (const float*)d_in[5];
  const float* Dv        = (const float*)d_in[6];
  const float* rms_w     = (const float*)d_in[7];
  const float* out_projw = (const float*)d_in[8];
  const float* conv_w    = (const float*)d_in[9];
  // d_in[10] = conv_b: per-channel constant cancels in batchnorm (and is zeros)
  const float* bn_gamma  = (const float*)d_in[11];
  const float* bn_beta   = (const float*)d_in[12];
  float* out = (float*)d_out;
  char* ws = (char*)d_ws;

  // workspace layout (bytes); WS_NEED = 174,481,408 (< 175,382,528 proven OK)
  __hip_bfloat16* zbuf = (__hip_bfloat16*)(ws + 0UL);           // 16384x1024 bf16 (33,554,432)
  __hip_bfloat16* xdt  = (__hip_bfloat16*)(ws + 33554432UL);    // 16384x1280 bf16 (41,943,040)
  __hip_bfloat16* xbcb = (__hip_bfloat16*)(ws + 75497472UL);    // 16384x1152 bf16 (37,748,736)
  __hip_bfloat16* ypb  = (__hip_bfloat16*)(ws + 113246208UL);   // 16384x1024 bf16 (33,554,432)
  __hip_bfloat16* xbf  = (__hip_bfloat16*)(ws + 146800640UL);   // 16,777,216
  __hip_bfloat16* w1b  = (__hip_bfloat16*)(ws + 163577856UL);   // 2,359,296
  __hip_bfloat16* w2b  = (__hip_bfloat16*)(ws + 165937152UL);   // 1,048,576 (rms_w folded)
  __hip_bfloat16* w3b  = (__hip_bfloat16*)(ws + 166985728UL);   // 6,291,456 (W' reordered)
  float* dtb           = (float*)(ws + 173277184UL);            // 1,048,576
  float* Aprod         = (float*)(ws + 174325760UL);            // 16,384
  float* stats         = (float*)(ws + 174342144UL);            // 8,192 (mean|rstd)
  float* rn            = (float*)(ws + 174350336UL);            // 65,536
  float* rnacc         = (float*)(ws + 174415872UL);            // 65,536
  const size_t WS_NEED = 174481408UL;

  const long outn = (long)BATCH * OC * DM;
  if (ws_size < WS_NEED) {
    fill_kernel<<<(int)((outn + 255) / 256), 256, 0, stream>>>(out, (float)(ws_size >> 20), outn);
    return;
  }

  // lifetime-disjoint aliases (pairwise-disjoint in time)
  __hip_bfloat16* Tbuf = xdt;       // T/H 4096x64x64 bf16 [ssd_chunk -> ssd_out]
  __hip_bfloat16* uTp  = xdt;       // 16x514x1024 bf16 [rnfin_pad/gemm2 -> gemm_conv]
  __hip_bfloat16* cbuf = zbuf;      // conv out 16x1024x512 bf16 [zbuf dead after ssd_out]
  float* statspart = (float*)ypb;   // [2][128][1024] f32 (1 MB) [ypb dead after gemm2]

  // fused prep (casts + reorders + rnacc zero)
  prep_kernel<<<14016, 256, 0, stream>>>(x, in_projw, out_projw, rms_w, conv_w,
                                         xbf, w1b, w2b, w3b, rnacc);

  // in_proj (single launch, split dest): z cols 0..1023 -> zbuf, rest -> xdt
  gemm1_kernel<<<dim3(128, 18), 256, 0, stream>>>(xbf, w1b, zbuf, xdt);
  // depthwise conv1d + silu + dt softplus (sliding window, 16-step walk)
  conv1d_slide_kernel<<<dim3(3, 64, BATCH), 256, 0, stream>>>(xdt, conv1dw, conv1db,
                                                              dt_bias, xbcb, dtb);
  // chunked SSD scan
  ssd_chunk_kernel<<<dim3(16, 16, 16), 256, 0, stream>>>(xbcb, dtb, A_log, ypb, Tbuf, Aprod);
  ssd_state_kernel<<<256, 1024, 0, stream>>>(Tbuf, Aprod);
  ssd_out_kernel<<<dim3(16, 16, 16), 256, 0, stream>>>(xbcb, dtb, A_log, Tbuf, zbuf,
                                                       Dv, ypb, rnacc);
  // rn finalize + uTp pad rows (Tbuf dead after ssd_out)
  rnfin_pad_kernel<<<192, 256, 0, stream>>>(rnacc, rn, uTp);
  // u = y @ out_proj^T, rn-scaled, written directly transposed (bf16) into uTp
  gemm2_trans_kernel<<<dim3(128, 4), 256, 0, stream>>>(ypb, w2b, rn, uTp);
  // final conv as GEMM (round-13 dbuf form) + non-contended bn partials
  gemm_conv_kernel<<<dim3(8, 4, 16), 256, 0, stream>>>(w3b, uTp, cbuf, statspart);
  // bn stats finalize (coalesced partial reduce) then apply + silu
  bnfin_kernel<<<4, 256, 0, stream>>>(statspart, stats);
  bn_silu_kernel<<<8192, 256, 0, stream>>>(cbuf, stats, bn_gamma, bn_beta, out);
}

// Round 16
// 272.643 us; speedup vs baseline: 1.0673x; 1.0673x over previous
//
#include <hip/hip_runtime.h>
#include <hip/hip_bf16.h>

#define BATCH 16
#define SEQ   1024
#define DM    512
#define DSTATE 64
#define DIN   1024
#define NH    16
#define CONVDIM 1152
#define DINPROJ 2192
#define NPAD  2304
#define XDTW  1280   // xdt buffer row width (cols 1024..2303 of zxbcdt)
#define OC    1024
#define EPSF  1e-5f

typedef __attribute__((ext_vector_type(8))) short short8;
typedef __attribute__((ext_vector_type(4))) float f32x4;

__device__ __forceinline__ void g2lds16(const __hip_bfloat16* g, __hip_bfloat16* l) {
  __builtin_amdgcn_global_load_lds(
      (const __attribute__((address_space(1))) void*)g,
      (__attribute__((address_space(3))) void*)l, 16, 0, 0);
}

__device__ __forceinline__ float siluf(float x) { return x / (1.f + expf(-x)); }
__device__ __forceinline__ float b2f(unsigned short u) {
  return __uint_as_float(((unsigned int)u) << 16);
}
__device__ __forceinline__ unsigned short f2b(float v) {
  __hip_bfloat16 h = __float2bfloat16(v);
  return __builtin_bit_cast(unsigned short, h);
}

// ---------------- gemm1: zxbcdt = x @ in_proj^T, split dest (z | xdt) --------
// double-buffered 2-phase (issue-early stage), 64 KB LDS, 1 barrier/iter.
__global__ __launch_bounds__(256) void gemm1_kernel(
    const __hip_bfloat16* __restrict__ A,
    const __hip_bfloat16* __restrict__ B,
    __hip_bfloat16* __restrict__ zbuf,
    __hip_bfloat16* __restrict__ xdt)
{
  __shared__ __hip_bfloat16 sAB[2][2][8192];  // [buf][A/B][128*64]
  const int tid  = threadIdx.x;
  const int lane = tid & 63;
  const int wid  = tid >> 6;
  const int wr = wid >> 1, wc = wid & 1;
  const long row0 = (long)blockIdx.x * 128;
  const int  col0 = blockIdx.y * 128;
  const __hip_bfloat16* Ab = A + row0 * 512;
  const __hip_bfloat16* Bb = B + (long)col0 * 512;

  auto stage = [&](int kt, int buf) {
#pragma unroll
    for (int it = 0; it < 4; ++it) {
      int idx = it * 256 + tid;
      int r = idx >> 3;
      int kk = (idx & 7) << 3;
      g2lds16(Ab + (long)r * 512 + kt + kk, &sAB[buf][0][idx * 8]);
      g2lds16(Bb + (long)r * 512 + kt + kk, &sAB[buf][1][idx * 8]);
    }
  };

  f32x4 acc[4][4] = {};
  stage(0, 0);
  __syncthreads();
  int cur = 0;
  for (int kt = 0; kt < 512; kt += 64) {
    if (kt + 64 < 512) stage(kt + 64, cur ^ 1);
    const __hip_bfloat16* sA = &sAB[cur][0][0];
    const __hip_bfloat16* sB = &sAB[cur][1][0];
#pragma unroll
    for (int kk = 0; kk < 64; kk += 32) {
      const int kl = kk + (lane >> 4) * 8;
      short8 af[4], bfr[4];
#pragma unroll
      for (int m = 0; m < 4; ++m)
        af[m] = *(const short8*)(sA + (wr * 64 + m * 16 + (lane & 15)) * 64 + kl);
#pragma unroll
      for (int n = 0; n < 4; ++n)
        bfr[n] = *(const short8*)(sB + (wc * 64 + n * 16 + (lane & 15)) * 64 + kl);
#pragma unroll
      for (int m = 0; m < 4; ++m)
#pragma unroll
        for (int n = 0; n < 4; ++n)
          acc[m][n] = __builtin_amdgcn_mfma_f32_16x16x32_bf16(af[m], bfr[n], acc[m][n], 0, 0, 0);
    }
    __syncthreads();  // drains stage loads; protects buf overwrite
    cur ^= 1;
  }

  __hip_bfloat16* Cb;
  int ldc, coff;
  if (col0 < 1024) { Cb = zbuf; ldc = 1024; coff = col0; }
  else             { Cb = xdt;  ldc = XDTW; coff = col0 - 1024; }
  const int rb = (int)row0 + wr * 64 + ((lane >> 4) << 2);
  const int cb = coff + wc * 64 + (lane & 15);
#pragma unroll
  for (int m = 0; m < 4; ++m)
#pragma unroll
    for (int n = 0; n < 4; ++n) {
      const int r = rb + m * 16, cc = cb + n * 16;
#pragma unroll
      for (int q = 0; q < 4; ++q)
        Cb[(long)(r + q) * ldc + cc] = __float2bfloat16(acc[m][n][q]);
    }
}

// ---------------- gemm2: u = y_raw @ (out_proj*rms_w)^T, rn-scaled, ----------
// writes uTp TRANSPOSED bf16. Double-buffered LDS (64 KB), 1 barrier/iter.
__global__ __launch_bounds__(256) void gemm2_trans_kernel(
    const __hip_bfloat16* __restrict__ A,     // ypb (unnormalized) [16384][1024]
    const __hip_bfloat16* __restrict__ B,     // w2b' [512][1024]
    const float* __restrict__ rn,             // [16384] row scales
    __hip_bfloat16* __restrict__ uTp)
{
  __shared__ unsigned short smem[2][2][8192];  // 64 KB: [buf][A/B][128*64]
  const int tid  = threadIdx.x;
  const int lane = tid & 63;
  const int wid  = tid >> 6;
  const int wr = wid >> 1, wc = wid & 1;
  const long row0 = (long)blockIdx.x * 128;   // (b,l) rows
  const int  col0 = blockIdx.y * 128;         // s cols
  const int  b  = (int)(row0 >> 10);
  const int  l0 = (int)(row0 & 1023);
  const __hip_bfloat16* Ab = A + row0 * 1024;
  const __hip_bfloat16* Bb = B + (long)col0 * 1024;

  auto stage = [&](int kt, int buf) {
#pragma unroll
    for (int it = 0; it < 4; ++it) {
      int idx = it * 256 + tid;
      int r = idx >> 3;
      int kk = (idx & 7) << 3;
      g2lds16(Ab + (long)r * 1024 + kt + kk, (__hip_bfloat16*)&smem[buf][0][idx * 8]);
      g2lds16(Bb + (long)r * 1024 + kt + kk, (__hip_bfloat16*)&smem[buf][1][idx * 8]);
    }
  };

  f32x4 acc[4][4] = {};
  stage(0, 0);
  __syncthreads();
  int cur = 0;
  for (int kt = 0; kt < 1024; kt += 64) {
    if (kt + 64 < 1024) stage(kt + 64, cur ^ 1);
    const __hip_bfloat16* sA = (const __hip_bfloat16*)&smem[cur][0][0];
    const __hip_bfloat16* sB = (const __hip_bfloat16*)&smem[cur][1][0];
#pragma unroll
    for (int kk = 0; kk < 64; kk += 32) {
      const int kl = kk + (lane >> 4) * 8;
      short8 af[4], bfr[4];
#pragma unroll
      for (int m = 0; m < 4; ++m)
        af[m] = *(const short8*)(sA + (wr * 64 + m * 16 + (lane & 15)) * 64 + kl);
#pragma unroll
      for (int n = 0; n < 4; ++n)
        bfr[n] = *(const short8*)(sB + (wc * 64 + n * 16 + (lane & 15)) * 64 + kl);
#pragma unroll
      for (int m = 0; m < 4; ++m)
#pragma unroll
        for (int n = 0; n < 4; ++n)
          acc[m][n] = __builtin_amdgcn_mfma_f32_16x16x32_bf16(af[m], bfr[n], acc[m][n], 0, 0, 0);
    }
    __syncthreads();  // drains stage loads; also protects buf overwrite
    cur ^= 1;
  }

  // rn-scale + transpose: acc(r,c) -> sT[c_local][r_local]  (c = s, r = l)
  unsigned short* sT = &smem[0][0][0];  // first 32 KB, contiguous 128*128
  const int rl = wr * 64 + ((lane >> 4) << 2);
  const int cl = wc * 64 + (lane & 15);
#pragma unroll
  for (int m = 0; m < 4; ++m) {
    float rnv[4];
#pragma unroll
    for (int q = 0; q < 4; ++q) rnv[q] = rn[row0 + rl + m * 16 + q];
#pragma unroll
    for (int n = 0; n < 4; ++n) {
      const int c = cl + n * 16;
#pragma unroll
      for (int q = 0; q < 4; ++q)
        sT[c * 128 + rl + m * 16 + q] = f2b(acc[m][n][q] * rnv[q]);
    }
  }
  __syncthreads();

  // coalesced out: wave w handles rows w*32..w*32+31; lane covers 2 l's
  unsigned short* up = (unsigned short*)uTp + (long)b * 514 * 1024;
  const int w = tid >> 6;
#pragma unroll
  for (int k = 0; k < 32; ++k) {
    const int row = w * 32 + k;  // s_local
    ushort2 o2;
    o2.x = sT[row * 128 + lane * 2];
    o2.y = sT[row * 128 + lane * 2 + 1];
    *(ushort2*)(up + (long)(col0 + row + 1) * 1024 + l0 + lane * 2) = o2;
  }
}

// ---------------- conv-as-GEMM: C[n] = W'(1024x3072) @ Bvirt[n]^T -------------
// Bvirt[n][s][k*1024+i] = uTp[n][s+k][i]; XCD swizzle; dbuf 64 KB; bf16 out.
// round-13 proven form: NO epilogue extras (both stats fusions regressed).
__global__ __launch_bounds__(256) void gemm_conv_kernel(
    const __hip_bfloat16* __restrict__ A,     // W' [1024][3072]
    const __hip_bfloat16* __restrict__ uTp,   // [16][514][1024]
    __hip_bfloat16* __restrict__ C)           // [16][1024][512] bf16
{
  // bijective swizzle: XCD k gets contiguous g-range -> 2 whole batches
  const int f = blockIdx.x + 8 * (blockIdx.y + 4 * blockIdx.z);  // 0..511
  const int g = (f & 7) * 64 + (f >> 3);
  const int bx = g & 7, by = (g >> 3) & 3, bz = g >> 5;

  __shared__ __hip_bfloat16 sAB[2][2][8192];  // 64 KB: [buf][A/B][128*64]
  const int tid  = threadIdx.x;
  const int lane = tid & 63;
  const int wid  = tid >> 6;
  const int wr = wid >> 1, wc = wid & 1;
  const int row0 = bx * 128;
  const int col0 = by * 128;
  const __hip_bfloat16* Ab = A + (long)row0 * 3072;
  const __hip_bfloat16* Ub = uTp + (long)bz * 514 * 1024;

  auto stage = [&](int kt, int buf) {
    const int seg = kt >> 10;        // k tap (0..2)
    const int io  = kt & 1023;       // i offset within tap
#pragma unroll
    for (int it = 0; it < 4; ++it) {
      int idx = it * 256 + tid;
      int r = idx >> 3;
      int kk = (idx & 7) << 3;
      g2lds16(Ab + (long)r * 3072 + kt + kk, &sAB[buf][0][idx * 8]);
      g2lds16(Ub + (long)(col0 + r + seg) * 1024 + io + kk, &sAB[buf][1][idx * 8]);
    }
  };

  f32x4 acc[4][4] = {};
  stage(0, 0);
  __syncthreads();
  int cur = 0;
  for (int kt = 0; kt < 3072; kt += 64) {
    if (kt + 64 < 3072) stage(kt + 64, cur ^ 1);
    const __hip_bfloat16* sA = &sAB[cur][0][0];
    const __hip_bfloat16* sB = &sAB[cur][1][0];
#pragma unroll
    for (int kk = 0; kk < 64; kk += 32) {
      const int kl = kk + (lane >> 4) * 8;
      short8 af[4], bfr[4];
#pragma unroll
      for (int m = 0; m < 4; ++m)
        af[m] = *(const short8*)(sA + (wr * 64 + m * 16 + (lane & 15)) * 64 + kl);
#pragma unroll
      for (int n = 0; n < 4; ++n)
        bfr[n] = *(const short8*)(sB + (wc * 64 + n * 16 + (lane & 15)) * 64 + kl);
#pragma unroll
      for (int m = 0; m < 4; ++m)
#pragma unroll
        for (int n = 0; n < 4; ++n)
          acc[m][n] = __builtin_amdgcn_mfma_f32_16x16x32_bf16(af[m], bfr[n], acc[m][n], 0, 0, 0);
    }
    __syncthreads();
    cur ^= 1;
  }

  __hip_bfloat16* Cb = C + (long)bz * OC * DM;
  const int rb = row0 + wr * 64 + ((lane >> 4) << 2);
  const int cb = col0 + wc * 64 + (lane & 15);
#pragma unroll
  for (int m = 0; m < 4; ++m)
#pragma unroll
    for (int n = 0; n < 4; ++n) {
      const int r = rb + m * 16, cc = cb + n * 16;
#pragma unroll
      for (int q = 0; q < 4; ++q)
        Cb[(long)(r + q) * DM + cc] = __float2bfloat16(acc[m][n][q]);
    }
}

// ---------------- fill (ws-guard diagnostics only) ---------------------------
__global__ __launch_bounds__(256) void fill_kernel(float* __restrict__ out, float v, long n) {
  long i = (long)blockIdx.x * 256 + threadIdx.x;
  if (i < n) out[i] = v;
}

// ---------------- fused prep: casts + reorders + rnacc zero ------------------
// blocks: [0,8192) x cast | [8192,9344) w1 pad-cast f4 | [9344,9856) w2*rms |
// [9856,13952) conv_w reorder | [13952,14016) rnacc zero
__global__ __launch_bounds__(256) void prep_kernel(
    const float* __restrict__ x, const float* __restrict__ w1,
    const float* __restrict__ w2, const float* __restrict__ rms_w,
    const float* __restrict__ w3,
    __hip_bfloat16* __restrict__ xbf, __hip_bfloat16* __restrict__ w1b,
    __hip_bfloat16* __restrict__ w2b, __hip_bfloat16* __restrict__ w3b,
    float* __restrict__ rnacc)
{
  const int bid = blockIdx.x;
  if (bid < 8192) {
    long i = (long)bid * 256 + threadIdx.x;   // 2,097,152 float4 groups
    float4 v = *(const float4*)(x + i * 4);
    __hip_bfloat16* o = xbf + i * 4;
    o[0] = __float2bfloat16(v.x);
    o[1] = __float2bfloat16(v.y);
    o[2] = __float2bfloat16(v.z);
    o[3] = __float2bfloat16(v.w);
  } else if (bid < 9344) {
    int i = (bid - 8192) * 256 + threadIdx.x;  // 294,912 float4 groups
    int r = i >> 7;                             // row (512-wide, 4-aligned)
    float4 v;
    if (r < DINPROJ) v = *(const float4*)(w1 + (long)i * 4);
    else { v.x = 0.f; v.y = 0.f; v.z = 0.f; v.w = 0.f; }
    __hip_bfloat16* o = w1b + (long)i * 4;
    o[0] = __float2bfloat16(v.x);
    o[1] = __float2bfloat16(v.y);
    o[2] = __float2bfloat16(v.z);
    o[3] = __float2bfloat16(v.w);
  } else if (bid < 9856) {
    int i = (bid - 9344) * 256 + threadIdx.x;  // 131072 groups of 4
    float4 v = *(const float4*)(w2 + (long)i * 4);
    float4 gw = *(const float4*)(rms_w + ((i * 4) & 1023));
    __hip_bfloat16* o = w2b + (long)i * 4;
    o[0] = __float2bfloat16(v.x * gw.x);
    o[1] = __float2bfloat16(v.y * gw.y);
    o[2] = __float2bfloat16(v.z * gw.z);
    o[3] = __float2bfloat16(v.w * gw.w);
  } else if (bid < 13952) {
    int t = (bid - 9856) * 256 + threadIdx.x;  // 1024*1024
    int o = t >> 10, i = t & 1023;
    const float* p = w3 + (long)o * 3072 + i * 3;
    __hip_bfloat16* q = w3b + (long)o * 3072 + i;
    q[0]    = __float2bfloat16(p[0]);
    q[1024] = __float2bfloat16(p[1]);
    q[2048] = __float2bfloat16(p[2]);
  } else {
    int i = (bid - 13952) * 256 + threadIdx.x;  // 16384 rnacc zeros
    rnacc[i] = 0.f;
  }
}

// ---------------- conv1d sliding-window, short walk (16) for occupancy -------
__global__ __launch_bounds__(256) void conv1d_slide_kernel(
    const __hip_bfloat16* __restrict__ xdt, const float* __restrict__ cw,
    const float* __restrict__ cb, const float* __restrict__ dt_bias,
    __hip_bfloat16* __restrict__ xbc, float* __restrict__ dtb)
{
  const int pair = blockIdx.x * 256 + threadIdx.x;
  const int c = pair * 2;                 // channel (even), < 1168 active
  if (c >= CONVDIM + NH) return;
  const int b  = blockIdx.z;
  const int l0 = blockIdx.y * 16;
  const long rowb = (long)b * SEQ;
  const unsigned short* src = (const unsigned short*)xdt + rowb * XDTW + c;

  if (c < CONVDIM) {
    const float4 wa = *(const float4*)(cw + c * 4);
    const float4 wb = *(const float4*)(cw + (c + 1) * 4);
    const float ba = cb[c], bb = cb[c + 1];
    float w0x, w0y, w1x, w1y, w2x, w2y;
    {
      ushort2 v;
      if (l0 >= 3) { v = *(const ushort2*)(src + (long)(l0 - 3) * XDTW); w0x = b2f(v.x); w0y = b2f(v.y); }
      else { w0x = 0.f; w0y = 0.f; }
      if (l0 >= 2) { v = *(const ushort2*)(src + (long)(l0 - 2) * XDTW); w1x = b2f(v.x); w1y = b2f(v.y); }
      else { w1x = 0.f; w1y = 0.f; }
      if (l0 >= 1) { v = *(const ushort2*)(src + (long)(l0 - 1) * XDTW); w2x = b2f(v.x); w2y = b2f(v.y); }
      else { w2x = 0.f; w2y = 0.f; }
    }
    unsigned short* dst = (unsigned short*)xbc + rowb * CONVDIM + c;
#pragma unroll
    for (int i = 0; i < 16; ++i) {
      const int l = l0 + i;
      const ushort2 v = *(const ushort2*)(src + (long)l * XDTW);
      const float xv0 = b2f(v.x), xv1 = b2f(v.y);
      float a0 = ba, a1 = bb;
      a0 += w0x * wa.x; a1 += w0y * wb.x;
      a0 += w1x * wa.y; a1 += w1y * wb.y;
      a0 += w2x * wa.z; a1 += w2y * wb.z;
      a0 += xv0 * wa.w; a1 += xv1 * wb.w;
      ushort2 o;
      o.x = f2b(siluf(a0));
      o.y = f2b(siluf(a1));
      *(ushort2*)(dst + (long)l * CONVDIM) = o;
      w0x = w1x; w0y = w1y; w1x = w2x; w1y = w2y; w2x = xv0; w2y = xv1;
    }
  } else {
    const int hh = c - CONVDIM;           // 0..14 (even)
    const float b0 = dt_bias[hh], b1 = dt_bias[hh + 1];
#pragma unroll
    for (int i = 0; i < 16; ++i) {
      const long l = l0 + i;
      const ushort2 v = *(const ushort2*)(src + l * XDTW);
      const float d0 = b2f(v.x) + b0, d1 = b2f(v.y) + b1;
      float2 o;
      o.x = fmaxf(d0, 0.f) + log1pf(expf(-fabsf(d0)));
      o.y = fmaxf(d1, 0.f) + log1pf(expf(-fabsf(d1)));
      *(float2*)(dtb + (rowb + l) * NH + hh) = o;
    }
  }
}

// ---------------- SSD chunked scan: phase 1 ----------------------------------
// outputs staged through dead LDS (sM/sBwT) -> coalesced ushort8 stores.
__global__ __launch_bounds__(256) void ssd_chunk_kernel(
    const __hip_bfloat16* __restrict__ xbc, const float* __restrict__ dtb,
    const float* __restrict__ A_log, __hip_bfloat16* __restrict__ ypre,
    __hip_bfloat16* __restrict__ Tbuf, float* __restrict__ Aprod)
{
  const int c = blockIdx.x, h = blockIdx.y, b = blockIdx.z;
  const int tid = threadIdx.x, lane = tid & 63, wid = tid >> 6;
  const int wr = wid >> 1, wc = wid & 1;
  const long r0 = (long)b * SEQ + c * 64;

  __shared__ unsigned short sB[64 * 72], sC[64 * 72], sXT[64 * 72],
                            sBwT[64 * 72], sM[64 * 72];
  __shared__ float sS[64], sDt[64];

  {
    const int j = tid >> 2, seg = (tid & 3) * 16;
    const unsigned short* row = (const unsigned short*)(xbc + (r0 + j) * CONVDIM);
    short8 v0 = *(const short8*)(row + DIN + seg);
    short8 v1 = *(const short8*)(row + DIN + seg + 8);
    *(short8*)&sB[j * 72 + seg] = v0;
    *(short8*)&sB[j * 72 + seg + 8] = v1;
    v0 = *(const short8*)(row + DIN + DSTATE + seg);
    v1 = *(const short8*)(row + DIN + DSTATE + seg + 8);
    *(short8*)&sC[j * 72 + seg] = v0;
    *(short8*)&sC[j * 72 + seg + 8] = v1;
    short8 x0 = *(const short8*)(row + h * 64 + seg);
    short8 x1 = *(const short8*)(row + h * 64 + seg + 8);
#pragma unroll
    for (int e = 0; e < 8; ++e) {
      sXT[(seg + e) * 72 + j] = (unsigned short)x0[e];
      sXT[(seg + 8 + e) * 72 + j] = (unsigned short)x1[e];
    }
  }
  if (tid < 64) {
    float dt = dtb[(r0 + tid) * NH + h];
    float s = -__expf(A_log[h]) * dt;
#pragma unroll
    for (int off = 1; off < 64; off <<= 1) {
      float o = __shfl_up(s, off);
      if (lane >= off) s += o;
    }
    sDt[tid] = dt;
    sS[tid] = s;
    if (tid == 63) Aprod[((b * 16 + h) * 16) + c] = __expf(s);
  }
  __syncthreads();

  {
    const int j = tid >> 2, n0 = (tid & 3) * 16;
    const float w = __expf(sS[63] - sS[j]) * sDt[j];
#pragma unroll
    for (int e = 0; e < 16; ++e)
      sBwT[(n0 + e) * 72 + j] = f2b(w * b2f(sB[j * 72 + n0 + e]));
  }
  {
    f32x4 acc1[2][2] = {};
#pragma unroll
    for (int kk = 0; kk < 64; kk += 32) {
      const int kl = kk + (lane >> 4) * 8;
      short8 af[2], bfr[2];
#pragma unroll
      for (int m = 0; m < 2; ++m)
        af[m] = *(const short8*)&sC[(wr * 32 + m * 16 + (lane & 15)) * 72 + kl];
#pragma unroll
      for (int n = 0; n < 2; ++n)
        bfr[n] = *(const short8*)&sB[(wc * 32 + n * 16 + (lane & 15)) * 72 + kl];
#pragma unroll
      for (int m = 0; m < 2; ++m)
#pragma unroll
        for (int n = 0; n < 2; ++n)
          acc1[m][n] = __builtin_amdgcn_mfma_f32_16x16x32_bf16(af[m], bfr[n], acc1[m][n], 0, 0, 0);
    }
    const int rq = (lane >> 4) * 4, cc = lane & 15;
#pragma unroll
    for (int m = 0; m < 2; ++m)
#pragma unroll
      for (int n = 0; n < 2; ++n)
#pragma unroll
        for (int q = 0; q < 4; ++q) {
          const int i = wr * 32 + m * 16 + rq + q;
          const int jj = wc * 32 + n * 16 + cc;
          float f = (jj <= i) ? __expf(sS[i] - sS[jj]) * sDt[jj] : 0.f;
          sM[i * 72 + jj] = f2b(acc1[m][n][q] * f);
        }
  }
  __syncthreads();

  f32x4 acc2[2][2] = {}, acc3[2][2] = {};
#pragma unroll
  for (int kk = 0; kk < 64; kk += 32) {
    const int kl = kk + (lane >> 4) * 8;
    short8 am[2], axB[2], axA[2], abw[2];
#pragma unroll
    for (int m = 0; m < 2; ++m) {
      am[m]  = *(const short8*)&sM[(wr * 32 + m * 16 + (lane & 15)) * 72 + kl];
      axA[m] = *(const short8*)&sXT[(wr * 32 + m * 16 + (lane & 15)) * 72 + kl];
    }
#pragma unroll
    for (int n = 0; n < 2; ++n) {
      axB[n] = *(const short8*)&sXT[(wc * 32 + n * 16 + (lane & 15)) * 72 + kl];
      abw[n] = *(const short8*)&sBwT[(wc * 32 + n * 16 + (lane & 15)) * 72 + kl];
    }
#pragma unroll
    for (int m = 0; m < 2; ++m)
#pragma unroll
      for (int n = 0; n < 2; ++n) {
        acc2[m][n] = __builtin_amdgcn_mfma_f32_16x16x32_bf16(am[m], axB[n], acc2[m][n], 0, 0, 0);
        acc3[m][n] = __builtin_amdgcn_mfma_f32_16x16x32_bf16(axA[m], abw[n], acc3[m][n], 0, 0, 0);
      }
  }
  __syncthreads();  // all waves done reading sM/sBwT -> safe to reuse
  {
    const int rq = (lane >> 4) * 4, cc = lane & 15;
#pragma unroll
    for (int m = 0; m < 2; ++m)
#pragma unroll
      for (int n = 0; n < 2; ++n)
#pragma unroll
        for (int q = 0; q < 4; ++q) {
          const int i = wr * 32 + m * 16 + rq + q;
          const int pj = wc * 32 + n * 16 + cc;
          sM[i * 72 + pj]   = f2b(acc2[m][n][q]);
          sBwT[i * 72 + pj] = f2b(acc3[m][n][q]);
        }
  }
  __syncthreads();
  {
    const int j = tid >> 2, seg = (tid & 3) * 16;
    unsigned short* yp = (unsigned short*)ypre + (r0 + j) * DIN + h * 64 + seg;
    *(short8*)yp       = *(const short8*)&sM[j * 72 + seg];
    *(short8*)(yp + 8) = *(const short8*)&sM[j * 72 + seg + 8];
    const long tb = (((long)(b * 16 + h)) * 16 + c) * 4096;
    unsigned short* tp = (unsigned short*)Tbuf + tb + j * 64 + seg;
    *(short8*)tp       = *(const short8*)&sBwT[j * 72 + seg];
    *(short8*)(tp + 8) = *(const short8*)&sBwT[j * 72 + seg + 8];
  }
}

// ---------------- SSD phase 2: sequential inter-chunk state ------------------
__global__ __launch_bounds__(1024) void ssd_state_kernel(
    __hip_bfloat16* __restrict__ Tbuf, const float* __restrict__ Aprod)
{
  const int bh = blockIdx.x;
  const int t = threadIdx.x;
  float h0 = 0.f, h1 = 0.f, h2 = 0.f, h3 = 0.f;
  unsigned short* base = (unsigned short*)Tbuf + (long)bh * 16 * 4096 + t * 4;
  for (int c = 0; c < 16; ++c) {
    unsigned short* p = base + (long)c * 4096;
    ushort4 tv = *(const ushort4*)p;
    ushort4 hv;
    hv.x = f2b(h0); hv.y = f2b(h1); hv.z = f2b(h2); hv.w = f2b(h3);
    *(ushort4*)p = hv;
    const float ap = Aprod[bh * 16 + c];
    h0 = h0 * ap + b2f(tv.x);
    h1 = h1 * ap + b2f(tv.y);
    h2 = h2 * ap + b2f(tv.z);
    h3 = h3 * ap + b2f(tv.w);
  }
}

// ---------------- SSD phase 3: Y += exp(s_i)*C@H^T + D*x; gate; rn partials --
// shfl row-reduce (round-11); output staged via dead sC -> coalesced stores.
__global__ __launch_bounds__(256) void ssd_out_kernel(
    const __hip_bfloat16* __restrict__ xbc, const float* __restrict__ dtb,
    const float* __restrict__ A_log, const __hip_bfloat16* __restrict__ Hbuf,
    const __hip_bfloat16* __restrict__ zbuf, const float* __restrict__ Dv,
    __hip_bfloat16* __restrict__ ypre, float* __restrict__ rnacc)
{
  const int c = blockIdx.x, h = blockIdx.y, b = blockIdx.z;
  const int tid = threadIdx.x, lane = tid & 63, wid = tid >> 6;
  const int wr = wid >> 1, wc = wid & 1;
  const long r0 = (long)b * SEQ + c * 64;

  __shared__ unsigned short sC[64 * 72], sH[64 * 72];
  __shared__ float sS[64];
  __shared__ float sRedW[2][64];   // [wc][row] per-wave partials (no conflicts)

  {
    const int j = tid >> 2, seg = (tid & 3) * 16;
    const unsigned short* row = (const unsigned short*)(xbc + (r0 + j) * CONVDIM);
    short8 v0 = *(const short8*)(row + DIN + DSTATE + seg);
    short8 v1 = *(const short8*)(row + DIN + DSTATE + seg + 8);
    *(short8*)&sC[j * 72 + seg] = v0;
    *(short8*)&sC[j * 72 + seg + 8] = v1;
    const unsigned short* hrow =
        (const unsigned short*)Hbuf + (((long)(b * 16 + h)) * 16 + c) * 4096 + j * 64;
    v0 = *(const short8*)(hrow + seg);
    v1 = *(const short8*)(hrow + seg + 8);
    *(short8*)&sH[j * 72 + seg] = v0;
    *(short8*)&sH[j * 72 + seg + 8] = v1;
  }
  if (tid < 64) {
    float dt = dtb[(r0 + tid) * NH + h];
    float s = -__expf(A_log[h]) * dt;
#pragma unroll
    for (int off = 1; off < 64; off <<= 1) {
      float o = __shfl_up(s, off);
      if (lane >= off) s += o;
    }
    sS[tid] = s;
  }
  __syncthreads();

  f32x4 acc[2][2] = {};
#pragma unroll
  for (int kk = 0; kk < 64; kk += 32) {
    const int kl = kk + (lane >> 4) * 8;
    short8 af[2], bfr[2];
#pragma unroll
    for (int m = 0; m < 2; ++m)
      af[m] = *(const short8*)&sC[(wr * 32 + m * 16 + (lane & 15)) * 72 + kl];
#pragma unroll
    for (int n = 0; n < 2; ++n)
      bfr[n] = *(const short8*)&sH[(wc * 32 + n * 16 + (lane & 15)) * 72 + kl];
#pragma unroll
    for (int m = 0; m < 2; ++m)
#pragma unroll
      for (int n = 0; n < 2; ++n)
        acc[m][n] = __builtin_amdgcn_mfma_f32_16x16x32_bf16(af[m], bfr[n], acc[m][n], 0, 0, 0);
  }
  __syncthreads();  // all MFMA reads of sC done -> reuse sC for output staging
  const float Dh = Dv[h];
  const int rq = (lane >> 4) * 4, cc = lane & 15;
  float rsum[2][4] = {};
#pragma unroll
  for (int m = 0; m < 2; ++m)
#pragma unroll
    for (int n = 0; n < 2; ++n)
#pragma unroll
      for (int q = 0; q < 4; ++q) {
        const int i = wr * 32 + m * 16 + rq + q;
        const int p = wc * 32 + n * 16 + cc;
        const long r = r0 + i;
        const long oidx = r * DIN + h * 64 + p;
        float yv = b2f(((const unsigned short*)ypre)[oidx]);
        float xv = b2f(((const unsigned short*)xbc)[r * CONVDIM + h * 64 + p]);
        float zv = b2f(((const unsigned short*)zbuf)[r * DIN + h * 64 + p]);
        yv += __expf(sS[i]) * acc[m][n][q] + Dh * xv;
        const float g = yv * siluf(zv);
        rsum[m][q] += g * g;
        sC[i * 72 + p] = f2b(g);
      }
  // wave-parallel row reduce: 16-lane column group -> shfl tree -> plain store
#pragma unroll
  for (int m = 0; m < 2; ++m)
#pragma unroll
    for (int q = 0; q < 4; ++q) {
      float v = rsum[m][q];
      v += __shfl_xor(v, 1);
      v += __shfl_xor(v, 2);
      v += __shfl_xor(v, 4);
      v += __shfl_xor(v, 8);
      if ((lane & 15) == 0)
        sRedW[wc][wr * 32 + m * 16 + rq + q] = v;
    }
  __syncthreads();
  {
    const int j = tid >> 2, seg = (tid & 3) * 16;
    unsigned short* yp = (unsigned short*)ypre + (r0 + j) * DIN + h * 64 + seg;
    *(short8*)yp       = *(const short8*)&sC[j * 72 + seg];
    *(short8*)(yp + 8) = *(const short8*)&sC[j * 72 + seg + 8];
  }
  if (tid < 64) atomicAdd(&rnacc[r0 + tid], sRedW[0][tid] + sRedW[1][tid]);
}

// ---------------- rn finalize + uTp pad-row zero (fused small launch) --------
__global__ __launch_bounds__(256) void rnfin_pad_kernel(
    const float* __restrict__ rnacc, float* __restrict__ rn,
    __hip_bfloat16* __restrict__ uTp)
{
  const int bid = blockIdx.x;
  if (bid < 64) {
    int i = bid * 256 + threadIdx.x;  // 16384
    rn[i] = rsqrtf(rnacc[i] * (1.f / DIN) + EPSF);
  } else {
    int t = (bid - 64) * 256 + threadIdx.x;  // 32768
    int n = t >> 11, w = t & 2047;
    long row = (w >> 10) ? 513 : 0;
    uTp[(long)n * 514 * 1024 + row * 1024 + (w & 1023)] = __float2bfloat16(0.f);
  }
}

// ---------------- batchnorm stats (bf16 input, 1 block/channel) --------------
__global__ __launch_bounds__(256) void bn_stats_kernel(
    const __hip_bfloat16* __restrict__ c, float* __restrict__ stats)
{
  const int o = blockIdx.x, t = threadIdx.x;
  float s = 0.f, s2 = 0.f;
  for (int n = 0; n < BATCH; ++n) {
    const unsigned short* base = (const unsigned short*)c + ((long)n * OC + o) * DM;
    ushort2 v = *(const ushort2*)(base + t * 2);
    float a = b2f(v.x), bb = b2f(v.y);
    s += a + bb;
    s2 += a * a + bb * bb;
  }
#pragma unroll
  for (int m = 32; m >= 1; m >>= 1) { s += __shfl_xor(s, m); s2 += __shfl_xor(s2, m); }
  __shared__ float r1[4], r2[4];
  if ((t & 63) == 0) { r1[t >> 6] = s; r2[t >> 6] = s2; }
  __syncthreads();
  if (t == 0) {
    s = r1[0] + r1[1] + r1[2] + r1[3];
    s2 = r2[0] + r2[1] + r2[2] + r2[3];
    float mean = s * (1.f / 8192.f);
    float var = s2 * (1.f / 8192.f) - mean * mean;
    stats[o] = mean;
    stats[OC + o] = rsqrtf(var + EPSF);
  }
}

__global__ __launch_bounds__(256) void bn_silu_kernel(
    const __hip_bfloat16* __restrict__ c, const float* __restrict__ stats,
    const float* __restrict__ gamma, const float* __restrict__ beta,
    float* __restrict__ out)
{
  long gid = (long)blockIdx.x * 256 + threadIdx.x;
  long base = gid * 4;
  int o = (int)((base >> 9) & (OC - 1));
  float mean = stats[o], rstd = stats[OC + o];
  float g = gamma[o] * rstd;
  float sh = beta[o] - mean * g;
  ushort4 v = *(const ushort4*)((const unsigned short*)c + base);
  float4 r;
  r.x = siluf(b2f(v.x) * g + sh);
  r.y = siluf(b2f(v.y) * g + sh);
  r.z = siluf(b2f(v.z) * g + sh);
  r.w = siluf(b2f(v.w) * g + sh);
  *(float4*)(out + base) = r;
}

// ---------------- launcher ---------------------------------------------------
extern "C" void kernel_launch(void* const* d_in, const int* in_sizes, int n_in,
                              void* d_out, int out_size, void* d_ws, size_t ws_size,
                              hipStream_t stream) {
  const float* x         = (const float*)d_in[0];
  const float* in_projw  = (const float*)d_in[1];
  const float* conv1dw   = (const float*)d_in[2];
  const float* conv1db   = (const float*)d_in[3];
  const float* dt_bias   = (const float*)d_in[4];
  const float* A_log     = (const float*)d_in[5];
  const float* Dv        = (const float*)d_in[6];
  const float* rms_w     = (const float*)d_in[7];
  const float* out_projw = (const float*)d_in[8];
  const float* conv_w    = (const float*)d_in[9];
  // d_in[10] = conv_b: per-channel constant cancels in batchnorm (and is zeros)
  const float* bn_gamma  = (const float*)d_in[11];
  const float* bn_beta   = (const float*)d_in[12];
  float* out = (float*)d_out;
  char* ws = (char*)d_ws;

  // workspace layout (bytes); WS_NEED = 174,481,408 (< 175,382,528 proven OK)
  __hip_bfloat16* zbuf = (__hip_bfloat16*)(ws + 0UL);           // 16384x1024 bf16 (33,554,432)
  __hip_bfloat16* xdt  = (__hip_bfloat16*)(ws + 33554432UL);    // 16384x1280 bf16 (41,943,040)
  __hip_bfloat16* xbcb = (__hip_bfloat16*)(ws + 75497472UL);    // 16384x1152 bf16 (37,748,736)
  __hip_bfloat16* ypb  = (__hip_bfloat16*)(ws + 113246208UL);   // 16384x1024 bf16 (33,554,432)
  __hip_bfloat16* xbf  = (__hip_bfloat16*)(ws + 146800640UL);   // 16,777,216
  __hip_bfloat16* w1b  = (__hip_bfloat16*)(ws + 163577856UL);   // 2,359,296
  __hip_bfloat16* w2b  = (__hip_bfloat16*)(ws + 165937152UL);   // 1,048,576 (rms_w folded)
  __hip_bfloat16* w3b  = (__hip_bfloat16*)(ws + 166985728UL);   // 6,291,456 (W' reordered)
  float* dtb           = (float*)(ws + 173277184UL);            // 1,048,576
  float* Aprod         = (float*)(ws + 174325760UL);            // 16,384
  float* stats         = (float*)(ws + 174342144UL);            // 8,192 (mean|rstd)
  float* rn            = (float*)(ws + 174350336UL);            // 65,536
  float* rnacc         = (float*)(ws + 174415872UL);            // 65,536
  const size_t WS_NEED = 174481408UL;

  const long outn = (long)BATCH * OC * DM;
  if (ws_size < WS_NEED) {
    fill_kernel<<<(int)((outn + 255) / 256), 256, 0, stream>>>(out, (float)(ws_size >> 20), outn);
    return;
  }

  // lifetime-disjoint aliases (all in the xdt region, pairwise-disjoint in time)
  __hip_bfloat16* Tbuf = xdt;    // T/H 4096x64x64 bf16 [ssd_chunk -> ssd_out; xdt dead after conv1d]
  __hip_bfloat16* uTp  = xdt;    // 16x514x1024 bf16 [rnfin_pad/gemm2 -> gemm_conv; Tbuf dead after ssd_out]
  __hip_bfloat16* cbuf = zbuf;   // conv out 16x1024x512 bf16 [zbuf dead after ssd_out]

  // fused prep (casts + reorders + rnacc zero)
  prep_kernel<<<14016, 256, 0, stream>>>(x, in_projw, out_projw, rms_w, conv_w,
                                         xbf, w1b, w2b, w3b, rnacc);

  // in_proj (single launch, split dest): z cols 0..1023 -> zbuf, rest -> xdt
  gemm1_kernel<<<dim3(128, 18), 256, 0, stream>>>(xbf, w1b, zbuf, xdt);
  // depthwise conv1d + silu + dt softplus (sliding window, 16-step walk)
  conv1d_slide_kernel<<<dim3(3, 64, BATCH), 256, 0, stream>>>(xdt, conv1dw, conv1db,
                                                              dt_bias, xbcb, dtb);
  // chunked SSD scan
  ssd_chunk_kernel<<<dim3(16, 16, 16), 256, 0, stream>>>(xbcb, dtb, A_log, ypb, Tbuf, Aprod);
  ssd_state_kernel<<<256, 1024, 0, stream>>>(Tbuf, Aprod);
  ssd_out_kernel<<<dim3(16, 16, 16), 256, 0, stream>>>(xbcb, dtb, A_log, Tbuf, zbuf,
                                                       Dv, ypb, rnacc);
  // rn finalize + uTp pad rows (Tbuf dead after ssd_out)
  rnfin_pad_kernel<<<192, 256, 0, stream>>>(rnacc, rn, uTp);
  // u = y @ out_proj^T, rn-scaled, written directly transposed (bf16) into uTp
  gemm2_trans_kernel<<<dim3(128, 4), 256, 0, stream>>>(ypb, w2b, rn, uTp);
  // final conv as GEMM over shifted uTp rows (round-13 proven dbuf form)
  gemm_conv_kernel<<<dim3(8, 4, 16), 256, 0, stream>>>(w3b, uTp, cbuf);
  // batchnorm: stats (1 block/channel) then apply + silu
  bn_stats_kernel<<<1024, 256, 0, stream>>>(cbuf, stats);
  bn_silu_kernel<<<8192, 256, 0, stream>>>(cbuf, stats, bn_gamma, bn_beta, out);
}